// Round 8
// baseline (4636.235 us; speedup 1.0000x reference)
//
#include <hip/hip_runtime.h>
#include <hip/hip_bf16.h>

// SpatialLSTM: B=64, T=2048, D=128, H=256 (4H=1024)
// R8: 1 batch per block, 8 slices x 64 batches = 512 blocks, 2 blocks/CU.
// U-slice (64KB) LDS-resident; W streamed from L2 per chunk; fused
// {f32 h, u32 counter} packets, parity double-buffered; lgkm-only barriers.
// One exchange per step; the co-resident block's compute hides the LLC RT.
#define BB 64
#define TT 2048
#define DD 128
#define HH 256
#define G4 1024
#define TC 16

typedef _Float16 half2_t __attribute__((ext_vector_type(2)));

#if __has_builtin(__builtin_amdgcn_fdot2)
#define FDOT2(a, b, c) __builtin_amdgcn_fdot2((a), (b), (c), false)
#else
__device__ __forceinline__ float FDOT2(half2_t a, half2_t b, float c) {
    return c + (float)a[0] * (float)b[0] + (float)a[1] * (float)b[1];
}
#endif

__device__ __forceinline__ half2_t u2h(unsigned int u) {
    union { unsigned int u; half2_t h; } x; x.u = u; return x.h;
}
__device__ __forceinline__ unsigned int pkf16(float a, float b) {
    union { _Float16 h[2]; unsigned int u; } x;
    x.h[0] = (_Float16)a; x.h[1] = (_Float16)b; return x.u;
}
__device__ __forceinline__ unsigned short f16b(float a) {
    union { _Float16 h; unsigned short u; } x; x.h = (_Float16)a; return x.u;
}
__device__ __forceinline__ float sigf(float x) {
    return 1.0f / (1.0f + __expf(-x));
}
__device__ __forceinline__ float tanh_fast(float x) {
    return 1.0f - 2.0f / (__expf(2.0f * x) + 1.0f);
}
// LDS-ordering-only barrier: no vmcnt(0) store-ack drain (nothing in-block
// reads our global stores; peers poll the LLC).
__device__ __forceinline__ void bar_lgkm() {
    asm volatile("s_waitcnt lgkmcnt(0)\n\ts_barrier" ::: "memory");
}

// ---- zero the packet buffer (counters must start < 1 every launch) ----
__global__ void zero_hglob(unsigned long long* hglob) {
    hglob[blockIdx.x * 256 + threadIdx.x] = 0ull;
}

// ---- pack slice-columns: src f32 [K][1024] -> dst f16 [8 slices][128 c][K]
// local col c of slice g <-> global gate col (c>>5)*256 + g*32 + (c&31)
__global__ void __launch_bounds__(128)
pack_slices(const float* __restrict__ src, unsigned short* __restrict__ dst, int K)
{
    const int g = blockIdx.x, kb = blockIdx.y, c = threadIdx.x;
    const int gc = ((c >> 5) << 8) + (g << 5) + (c & 31);
    unsigned int* d32 = (unsigned int*)dst;
    const int dbase = ((g << 7) + c) * K + kb * 64;     // half index, even
    for (int kk = 0; kk < 64; kk += 2) {
        const float a = src[(size_t)(kb * 64 + kk) * G4 + gc];
        const float b = src[(size_t)(kb * 64 + kk + 1) * G4 + gc];
        d32[(dbase + kk) >> 1] = pkf16(a, b);
    }
}

// ============================ main kernel ===================================
// grid 512: b = blk & 63 (batch), g = blk >> 6 (slice: 32 h-cols, 128 gate cols)
// clique = 8 blocks {b + 64*g}; all share blk%8 -> XCD-local under round-robin.
extern "C" __global__ void __launch_bounds__(512, 4)
lstm_solo(const float* __restrict__ X, const unsigned short* __restrict__ Upack,
          const unsigned short* __restrict__ Wpack, const float* __restrict__ bias,
          const float* __restrict__ h0, const float* __restrict__ c0,
          unsigned long long* __restrict__ hglob, float* __restrict__ out)
{
    __shared__ __align__(16) uint4 Ulds4[128 * 32];      // 64 KB, swizzled
    __shared__ float xw[TC][128];                        // 8 KB
    __shared__ __align__(16) unsigned short Xs[TC * DD]; // 4 KB (f16)
    __shared__ float gvp[4][128];                        // 2 KB partials
    __shared__ __align__(16) unsigned short hsh[HH];     // 512 B (f16 h)
    // total 78.5 KB -> 2 blocks/CU

    const int b = blockIdx.x & 63;
    const int g = blockIdx.x >> 6;
    const int tid = threadIdx.x;
    const int wave = tid >> 6, lane = tid & 63;
    const int c = tid & 127, s = tid >> 7;               // local col, k-quarter

    // ---- stage U-slice into LDS (swizzle granule gr ^ (c&31)) ----
    {
        const uint4* Usrc = (const uint4*)(Upack + (size_t)g * 32768);
        #pragma unroll
        for (int i = 0; i < 8; ++i) {
            const int idx = i * 512 + tid;               // cc*32 + gr
            const int cc = idx >> 5, gr = idx & 31;
            Ulds4[cc * 32 + (gr ^ (cc & 31))] = Usrc[idx];
        }
    }
    if (tid < HH) hsh[tid] = f16b(h0[(size_t)b * HH + tid]);
    float c_reg = 0.0f, h_last = 0.0f;
    if (wave == 0 && lane < 32) {
        c_reg = c0[(size_t)b * HH + (g << 5) + lane];
        h_last = h0[(size_t)b * HH + (g << 5) + lane];
    }
    const float bc = bias[((c >> 5) << 8) + (g << 5) + (c & 31)];
    __syncthreads();

    // W col c of slice g: 128 halfs = 16 uint4, streamed from L2 each chunk
    const uint4* Wcol = (const uint4*)(Wpack + (size_t)g * 16384) + (size_t)c * 16;
    const size_t obase = (size_t)b * TT * HH + (g << 5);
    const int slotbase = ((b << 3) + g) << 1;            // *32 packets

    for (int chunk = 0; chunk < TT / TC; ++chunk) {
        const int t0 = chunk * TC;

        // ---- stage X chunk (f32 -> f16 pairs): 512 threads x float4 ----
        {
            const float4 xv = ((const float4*)(X + ((size_t)b * TT + t0) * DD))[tid];
            ((uint2*)Xs)[tid] = make_uint2(pkf16(xv.x, xv.y), pkf16(xv.z, xv.w));
        }
        bar_lgkm();

        // ---- xw[t][c] = X@Wslice + bias; thread (c,s): t in [4s, 4s+4) ----
        {
            float acc[4];
            #pragma unroll
            for (int t = 0; t < 4; ++t) acc[t] = bc;
            #pragma unroll
            for (int k8 = 0; k8 < 16; ++k8) {
                const uint4 w4 = Wcol[k8];               // global (L2-hot)
                #pragma unroll
                for (int t = 0; t < 4; ++t) {
                    const uint4 xg = *(const uint4*)((const char*)Xs +
                                     ((s * 4 + t) << 8) + (k8 << 4));
                    acc[t] = FDOT2(u2h(xg.x), u2h(w4.x), acc[t]);
                    acc[t] = FDOT2(u2h(xg.y), u2h(w4.y), acc[t]);
                    acc[t] = FDOT2(u2h(xg.z), u2h(w4.z), acc[t]);
                    acc[t] = FDOT2(u2h(xg.w), u2h(w4.w), acc[t]);
                }
            }
            #pragma unroll
            for (int t = 0; t < 4; ++t) xw[s * 4 + t][c] = acc[t];
        }
        bar_lgkm();

        // ---- TC recurrent steps: {phase A | exchange} ----
        for (int tt2 = 0; tt2 < TC; ++tt2) {
            const int tau = t0 + tt2;

            // phase A: partial dot over this thread's k-quarter
            {
                float a = (s == 0) ? xw[tt2][c] : 0.0f;
                #pragma unroll
                for (int ii = 0; ii < 8; ++ii) {
                    const uint4 ug = Ulds4[c * 32 + ((s * 8 + ii) ^ (c & 31))];
                    const uint4 hg = *(const uint4*)((const char*)hsh + (s << 7) + (ii << 4));
                    a = FDOT2(u2h(ug.x), u2h(hg.x), a);
                    a = FDOT2(u2h(ug.y), u2h(hg.y), a);
                    a = FDOT2(u2h(ug.z), u2h(hg.z), a);
                    a = FDOT2(u2h(ug.w), u2h(hg.w), a);
                }
                gvp[s][c] = a;
            }
            bar_lgkm();

            // exchange: wave0 gates+publish; waves 1-7 poll 7 peers
            const int par = (tau + 1) & 1;
            if (wave == 0) {
                if (lane < 32) {
                    const int j = lane;
                    float gi = 0.f, gf = 0.f, gg = 0.f, go = 0.f;
                    #pragma unroll
                    for (int q = 0; q < 4; ++q) {
                        gi += gvp[q][j];       gf += gvp[q][32 + j];
                        gg += gvp[q][64 + j];  go += gvp[q][96 + j];
                    }
                    const float it = sigf(gi), ft = sigf(gf);
                    const float gt = tanh_fast(gg), ot = sigf(go);
                    c_reg = fmaf(ft, c_reg, it * gt);
                    const float hn = ot * tanh_fast(c_reg);
                    h_last = hn;
                    const unsigned long long pkt =
                        ((unsigned long long)(unsigned)(tau + 1) << 32) |
                        (unsigned long long)__float_as_uint(hn);
                    __hip_atomic_store(&hglob[(size_t)(slotbase + par) * 32 + j],
                                       pkt, __ATOMIC_RELAXED, __HIP_MEMORY_SCOPE_AGENT);
                    out[obase + (size_t)tau * HH + j] = hn;
                    hsh[(g << 5) + j] = f16b(hn);
                }
            } else if (tau < TT - 1 && lane < 32) {
                const int pg = (g + wave) & 7;
                const unsigned long long* q =
                    &hglob[(size_t)((((b << 3) + pg) << 1) + par) * 32 + lane];
                unsigned long long v; int spins = 0;
                do {
                    v = __hip_atomic_load(q, __ATOMIC_RELAXED, __HIP_MEMORY_SCOPE_AGENT);
                    if (++spins > (1 << 20)) break;      // anti-hang: fail fast
                } while ((unsigned)(v >> 32) != (unsigned)(tau + 1));
                hsh[(pg << 5) + lane] = f16b(__uint_as_float((unsigned)v));
            }
            bar_lgkm();
        }
    }

    if (wave == 0 && lane < 32) {
        const size_t base = (size_t)BB * TT * HH;
        out[base + (size_t)b * HH + (g << 5) + lane] = h_last;
        out[base + (size_t)BB * HH + (size_t)b * HH + (g << 5) + lane] = c_reg;
    }
}

// ===================== R2 fallback (f32, no workspace) ======================
extern "C" __global__ void __launch_bounds__(512)
lstm_persist(const float* __restrict__ X, const float* __restrict__ W,
             const float* __restrict__ U, const float* __restrict__ bias,
             const float* __restrict__ h0, const float* __restrict__ c0,
             float* __restrict__ out)
{
    __shared__ float xw[TC][G4];
    __shared__ float Xs[TC][DD];
    __shared__ float hsh[HH];
    __shared__ float gv[G4];

    const int b = blockIdx.x;
    const int tid = threadIdx.x;
    const float2* __restrict__ U2 = reinterpret_cast<const float2*>(U);
    const float2* __restrict__ W2 = reinterpret_cast<const float2*>(W);

    float c_reg = 0.0f;
    if (tid < HH) { hsh[tid] = h0[b * HH + tid]; c_reg = c0[b * HH + tid]; }
    const float2 bs = reinterpret_cast<const float2*>(bias)[tid];
    __syncthreads();

    for (int chunk = 0; chunk < TT / TC; ++chunk) {
        const int t0 = chunk * TC;
        {
            const float4* src = reinterpret_cast<const float4*>(X + ((size_t)b * TT + t0) * DD);
            float4* dst = reinterpret_cast<float4*>(&Xs[0][0]);
            for (int i = tid; i < TC * DD / 4; i += 512) dst[i] = src[i];
        }
        __syncthreads();
        float acc0[TC], acc1[TC];
        #pragma unroll
        for (int t = 0; t < TC; ++t) { acc0[t] = bs.x; acc1[t] = bs.y; }
        for (int kk = 0; kk < DD; kk += 4) {
            const float2 w0 = W2[(size_t)(kk + 0) * (G4 / 2) + tid];
            const float2 w1 = W2[(size_t)(kk + 1) * (G4 / 2) + tid];
            const float2 w2 = W2[(size_t)(kk + 2) * (G4 / 2) + tid];
            const float2 w3 = W2[(size_t)(kk + 3) * (G4 / 2) + tid];
            #pragma unroll
            for (int t = 0; t < TC; ++t) {
                const float4 xv = *reinterpret_cast<const float4*>(&Xs[t][kk]);
                acc0[t] = fmaf(xv.x, w0.x, acc0[t]); acc1[t] = fmaf(xv.x, w0.y, acc1[t]);
                acc0[t] = fmaf(xv.y, w1.x, acc0[t]); acc1[t] = fmaf(xv.y, w1.y, acc1[t]);
                acc0[t] = fmaf(xv.z, w2.x, acc0[t]); acc1[t] = fmaf(xv.z, w2.y, acc1[t]);
                acc0[t] = fmaf(xv.w, w3.x, acc0[t]); acc1[t] = fmaf(xv.w, w3.y, acc1[t]);
            }
        }
        #pragma unroll
        for (int t = 0; t < TC; ++t)
            *reinterpret_cast<float2*>(&xw[t][2 * tid]) = make_float2(acc0[t], acc1[t]);
        __syncthreads();

        for (int t = 0; t < TC; ++t) {
            const float2 x2 = *reinterpret_cast<const float2*>(&xw[t][2 * tid]);
            float a0 = x2.x, a1 = x2.y;
            #pragma unroll 4
            for (int k = 0; k < HH; k += 4) {
                const float4 hk = *reinterpret_cast<const float4*>(&hsh[k]);
                const float2 u0 = U2[(size_t)(k + 0) * (G4 / 2) + tid];
                const float2 u1 = U2[(size_t)(k + 1) * (G4 / 2) + tid];
                const float2 u2 = U2[(size_t)(k + 2) * (G4 / 2) + tid];
                const float2 u3 = U2[(size_t)(k + 3) * (G4 / 2) + tid];
                a0 = fmaf(hk.x, u0.x, a0); a1 = fmaf(hk.x, u0.y, a1);
                a0 = fmaf(hk.y, u1.x, a0); a1 = fmaf(hk.y, u1.y, a1);
                a0 = fmaf(hk.z, u2.x, a0); a1 = fmaf(hk.z, u2.y, a1);
                a0 = fmaf(hk.w, u3.x, a0); a1 = fmaf(hk.w, u3.y, a1);
            }
            *reinterpret_cast<float2*>(&gv[2 * tid]) = make_float2(a0, a1);
            __syncthreads();
            if (tid < HH) {
                const float it = sigf(gv[tid]);
                const float ft = sigf(gv[tid + HH]);
                const float gt = tanh_fast(gv[tid + 2 * HH]);
                const float ot = sigf(gv[tid + 3 * HH]);
                c_reg = fmaf(ft, c_reg, it * gt);
                const float hn = ot * tanh_fast(c_reg);
                hsh[tid] = hn;
                out[((size_t)b * TT + (t0 + t)) * HH + tid] = hn;
            }
            __syncthreads();
        }
    }
    if (tid < HH) {
        const size_t base = (size_t)BB * TT * HH;
        out[base + (size_t)b * HH + tid] = hsh[tid];
        out[base + (size_t)BB * HH + (size_t)b * HH + tid] = c_reg;
    }
}

extern "C" void kernel_launch(void* const* d_in, const int* in_sizes, int n_in,
                              void* d_out, int out_size, void* d_ws, size_t ws_size,
                              hipStream_t stream) {
    const float* X    = (const float*)d_in[0];
    const float* W    = (const float*)d_in[1];
    const float* U    = (const float*)d_in[2];
    const float* bias = (const float*)d_in[3];
    const float* h0   = (const float*)d_in[4];
    const float* c0   = (const float*)d_in[5];
    float* out = (float*)d_out;
    (void)in_sizes; (void)n_in; (void)out_size;

    // --- R8 path: 1 MB workspace ---
    const size_t upk = 512 * 1024;     // Upack f16 [8][128][256]
    const size_t wpk = 256 * 1024;     // Wpack f16 [8][128][128]
    const size_t hgl = 256 * 1024;     // hglob u64 [64][8][2][32]
    if (ws_size >= upk + wpk + hgl) {
        unsigned short* Upack = (unsigned short*)d_ws;
        unsigned short* Wpack = (unsigned short*)((char*)d_ws + upk);
        unsigned long long* hglob = (unsigned long long*)((char*)d_ws + upk + wpk);
        zero_hglob<<<dim3(128), dim3(256), 0, stream>>>(hglob);
        pack_slices<<<dim3(8, 4), dim3(128), 0, stream>>>(U, Upack, 256);
        pack_slices<<<dim3(8, 2), dim3(128), 0, stream>>>(W, Wpack, 128);
        lstm_solo<<<dim3(512), dim3(512), 0, stream>>>(
            X, Upack, Wpack, bias, h0, c0, hglob, out);
        return;
    }

    // --- R2 fallback: no workspace ---
    lstm_persist<<<dim3(BB), dim3(512), 0, stream>>>(X, W, U, bias, h0, c0, out);
}